// Round 4
// baseline (298.778 us; speedup 1.0000x reference)
//
#include <hip/hip_runtime.h>
#include <math.h>

#define LQ 40000
#define DMODEL 256
#define NHD 8
#define NPT 4
#define DHD 32
#define HSP 200
#define WSP 200

typedef short s16x8 __attribute__((ext_vector_type(8)));
typedef float f32x4 __attribute__((ext_vector_type(4)));

__device__ __forceinline__ unsigned short f2b(float f) {
    unsigned u = __builtin_bit_cast(unsigned, f);
    u += 0x7FFFu + ((u >> 16) & 1u);   // round-to-nearest-even
    return (unsigned short)(u >> 16);
}
__device__ __forceinline__ float b2f(unsigned short u) {
    return __builtin_bit_cast(float, ((unsigned)u) << 16);
}
__device__ __forceinline__ unsigned short pk8(const float4& v0, const float4& v1,
                                              unsigned short* o) {
    o[0] = f2b(v0.x); o[1] = f2b(v0.y); o[2] = f2b(v0.z); o[3] = f2b(v0.w);
    o[4] = f2b(v1.x); o[5] = f2b(v1.y); o[6] = f2b(v1.z); o[7] = f2b(v1.w);
    return 0;
}

// ---------------------------------------------------------------------------
// One-barrier MFMA GEMM. C[64 x NCOLS] per block, K = 256 staged entirely in
// LDS in fragment-native layout: frag-block fb = ks*4 + m holds the 1 KiB
// A-fragment data for (strip m, k-slice ks); lane l's 16 B at (fb*64+l)*16.
// Conflict-free b128 reads/writes. B (fp32 weights, virtual [W1;W2] split)
// lives in registers: wave w owns col-tiles {w + 4j}, 8 frags each.
// CMODE 0: C fp32 row-major [M x NCOLS]. CMODE 1: C bf16 "value" layout
// [head][pixel][32ch] (NCOLS must be 256).
// ---------------------------------------------------------------------------
template <int NCOLS, int TPW, typename AT, bool HasA2, int CMODE>
__global__ __launch_bounds__(256, 2) void gemm_mfma(
    const AT* __restrict__ A, const float* __restrict__ A2,
    const float* __restrict__ W1, const float* __restrict__ b1,
    const float* __restrict__ W2, const float* __restrict__ b2, int split,
    void* __restrict__ Cv)
{
    constexpr int NT = NCOLS / 16;
    __shared__ __align__(16) unsigned short As[64 * 256];

    const int t = threadIdx.x;
    const int wave = t >> 6, lane = t & 63;
    const int l15 = lane & 15, quad = lane >> 4;
    const size_t rowBase = (size_t)blockIdx.x * 64;

    // ---- issue all A staging loads (independent, fill the memory queue) ----
    float4 sv0[8], sv1[8];
    uint4  sb[8];
#pragma unroll
    for (int rep = 0; rep < 8; ++rep) {
        int fb = rep * 4 + wave;
        int m = fb & 3, ks = fb >> 2;
        size_t src = (rowBase + m * 16 + l15) * 256 + ks * 32 + quad * 8;
        if constexpr (sizeof(AT) == 4) {
            const float* Ap = (const float*)A + src;
            sv0[rep] = *(const float4*)Ap;
            sv1[rep] = *(const float4*)(Ap + 4);
            if constexpr (HasA2) {
                const float* Bp = A2 + src;
                float4 w0 = *(const float4*)Bp;
                float4 w1 = *(const float4*)(Bp + 4);
                sv0[rep].x += w0.x; sv0[rep].y += w0.y;
                sv0[rep].z += w0.z; sv0[rep].w += w0.w;
                sv1[rep].x += w1.x; sv1[rep].y += w1.y;
                sv1[rep].z += w1.z; sv1[rep].w += w1.w;
            }
        } else {
            sb[rep] = *(const uint4*)((const unsigned short*)A + src);
        }
    }

    // ---- load B fragments into registers (fp32 weights, L2-resident) ----
    s16x8 bf[TPW][8];
#pragma unroll
    for (int j = 0; j < TPW; ++j) {
        int c = wave + 4 * j;
        if (c < NT) {
            int col = c * 16 + l15;
            const float* Wp = (col < split) ? (W1 + (size_t)col * 256)
                                            : (W2 + (size_t)(col - split) * 256);
#pragma unroll
            for (int ks = 0; ks < 8; ++ks) {
                float4 w0 = *(const float4*)(Wp + ks * 32 + quad * 8);
                float4 w1 = *(const float4*)(Wp + ks * 32 + quad * 8 + 4);
                union { unsigned short u[8]; s16x8 v; } tmp;
                pk8(w0, w1, tmp.u);
                bf[j][ks] = tmp.v;
            }
        }
    }

    // ---- convert + write A tile to LDS ----
#pragma unroll
    for (int rep = 0; rep < 8; ++rep) {
        int fb = rep * 4 + wave;
        unsigned short* dst = &As[(fb * 64 + lane) * 8];
        if constexpr (sizeof(AT) == 4) {
            union { unsigned short u[8]; uint4 v; } tmp;
            pk8(sv0[rep], sv1[rep], tmp.u);
            *(uint4*)dst = tmp.v;
        } else {
            *(uint4*)dst = sb[rep];
        }
    }
    __syncthreads();

    // ---- compute: 4 strips x TPW tiles, 8 chained MFMAs each ----
#pragma unroll
    for (int m = 0; m < 4; ++m) {
        s16x8 a[8];
#pragma unroll
        for (int ks = 0; ks < 8; ++ks)
            a[ks] = *(const s16x8*)&As[(((ks << 2) | m) * 64 + lane) * 8];
#pragma unroll
        for (int j = 0; j < TPW; ++j) {
            int c = wave + 4 * j;
            if (c < NT) {
                f32x4 acc = (f32x4){0.f, 0.f, 0.f, 0.f};
#pragma unroll
                for (int ks = 0; ks < 8; ++ks)
                    acc = __builtin_amdgcn_mfma_f32_16x16x32_bf16(a[ks], bf[j][ks],
                                                                  acc, 0, 0, 0);
                int col = c * 16 + l15;
                float bb = (col < split) ? b1[col] : b2[col - split];
#pragma unroll
                for (int r2 = 0; r2 < 4; ++r2) {
                    size_t row = rowBase + m * 16 + quad * 4 + r2;
                    float v = acc[r2] + bb;
                    if constexpr (CMODE == 1) {
                        // value layout: [head][pixel][32ch]
                        ((unsigned short*)Cv)[(((size_t)(c >> 1) * LQ + row) << 5)
                                              + ((c & 1) << 4) + l15] = f2b(v);
                    } else {
                        ((float*)Cv)[row * NCOLS + col] = v;
                    }
                }
            }
        }
    }
}

// ---------------------------------------------------------------------------
// Deformable sampling. Block = 256 thr, 8 queries per block.
// Phase 1: thread (qi,h,p) -> fused corner weights (softmax*bilinear*valid)
//          + clamped pixel element-offsets (pix*32) in LDS.
// Phase 2: thread (qq,h,d8): 2 queries, 4ch via uint2 loads; value layout
//          [head][pixel][32ch] puts x0/x0+1 corners in adjacent 64 B blocks.
// ---------------------------------------------------------------------------
__global__ __launch_bounds__(256) void sample_kernel(
    const float* __restrict__ raw, const float* __restrict__ rp,
    const unsigned short* __restrict__ value, unsigned short* __restrict__ outa)
{
    __shared__ int4   sIdx[8][8][4];
    __shared__ float4 sW[8][8][4];

    const int t = threadIdx.x;
    {   // phase 1
        const int qi = t >> 5, h = (t >> 2) & 7, p = t & 3;
        const int q = blockIdx.x * 8 + qi;
        const float* r = raw + (size_t)q * 96;
        float l0 = r[64 + h * 4 + 0], l1 = r[64 + h * 4 + 1];
        float l2 = r[64 + h * 4 + 2], l3 = r[64 + h * 4 + 3];
        float mx = fmaxf(fmaxf(l0, l1), fmaxf(l2, l3));
        float e0 = __expf(l0 - mx), e1 = __expf(l1 - mx);
        float e2 = __expf(l2 - mx), e3 = __expf(l3 - mx);
        float inv = 1.f / (e0 + e1 + e2 + e3);
        float ep = (p == 0) ? e0 : (p == 1) ? e1 : (p == 2) ? e2 : e3;
        float wp = ep * inv;

        float x = rp[(size_t)q * 2 + 0] * (float)WSP - 0.5f + r[h * 8 + p * 2 + 0];
        float y = rp[(size_t)q * 2 + 1] * (float)HSP - 0.5f + r[h * 8 + p * 2 + 1];
        float x0f = floorf(x), y0f = floorf(y);
        int x0 = (int)x0f, y0 = (int)y0f;
        float lw = x - x0f, lh = y - y0f;
        float cw[4] = {(1.f - lh) * (1.f - lw), (1.f - lh) * lw,
                       lh * (1.f - lw), lh * lw};
        int4 I; float4 W;
        int* Ip = &I.x; float* Wp = &W.x;
#pragma unroll
        for (int c = 0; c < 4; ++c) {
            int cx = x0 + (c & 1), cy = y0 + (c >> 1);
            bool valid = (cx >= 0) & (cx < WSP) & (cy >= 0) & (cy < HSP);
            int ccx = cx < 0 ? 0 : (cx > WSP - 1 ? WSP - 1 : cx);
            int ccy = cy < 0 ? 0 : (cy > HSP - 1 ? HSP - 1 : cy);
            Ip[c] = (ccy * WSP + ccx) * DHD;     // element offset within head plane
            Wp[c] = valid ? cw[c] * wp : 0.f;
        }
        sIdx[qi][h][p] = I;
        sW[qi][h][p] = W;
    }
    __syncthreads();

    // phase 2
    const int qq = t >> 6, h = (t >> 3) & 7, d8 = t & 7;
    const unsigned short* vp = value + (size_t)h * LQ * DHD + d8 * 4;
#pragma unroll
    for (int e = 0; e < 2; ++e) {
        int qi = qq * 2 + e;
        float a0 = 0.f, a1 = 0.f, a2 = 0.f, a3 = 0.f;
#pragma unroll
        for (int p = 0; p < 4; ++p) {
            int4 I = sIdx[qi][h][p];
            float4 W = sW[qi][h][p];
            uint2 g0 = *(const uint2*)(vp + I.x);
            uint2 g1 = *(const uint2*)(vp + I.y);
            uint2 g2 = *(const uint2*)(vp + I.z);
            uint2 g3 = *(const uint2*)(vp + I.w);
            a0 += W.x * b2f((unsigned short)g0.x);
            a1 += W.x * b2f((unsigned short)(g0.x >> 16));
            a2 += W.x * b2f((unsigned short)g0.y);
            a3 += W.x * b2f((unsigned short)(g0.y >> 16));
            a0 += W.y * b2f((unsigned short)g1.x);
            a1 += W.y * b2f((unsigned short)(g1.x >> 16));
            a2 += W.y * b2f((unsigned short)g1.y);
            a3 += W.y * b2f((unsigned short)(g1.y >> 16));
            a0 += W.z * b2f((unsigned short)g2.x);
            a1 += W.z * b2f((unsigned short)(g2.x >> 16));
            a2 += W.z * b2f((unsigned short)g2.y);
            a3 += W.z * b2f((unsigned short)(g2.y >> 16));
            a0 += W.w * b2f((unsigned short)g3.x);
            a1 += W.w * b2f((unsigned short)(g3.x >> 16));
            a2 += W.w * b2f((unsigned short)g3.y);
            a3 += W.w * b2f((unsigned short)(g3.y >> 16));
        }
        int q = blockIdx.x * 8 + qi;
        union { unsigned short u[4]; uint2 v; } o;
        o.u[0] = f2b(a0); o.u[1] = f2b(a1); o.u[2] = f2b(a2); o.u[3] = f2b(a3);
        *(uint2*)&outa[(size_t)q * DMODEL + h * DHD + d8 * 4] = o.v;
    }
}

extern "C" void kernel_launch(void* const* d_in, const int* in_sizes, int n_in,
                              void* d_out, int out_size, void* d_ws, size_t ws_size,
                              hipStream_t stream)
{
    const float* query         = (const float*)d_in[0];
    const float* query_pos     = (const float*)d_in[1];
    const float* ref_points    = (const float*)d_in[2];
    const float* input_flatten = (const float*)d_in[3];
    const float* W_value       = (const float*)d_in[4];
    const float* b_value       = (const float*)d_in[5];
    const float* W_off         = (const float*)d_in[6];
    const float* b_off         = (const float*)d_in[7];
    const float* W_attn        = (const float*)d_in[8];
    const float* b_attn        = (const float*)d_in[9];
    const float* W_out         = (const float*)d_in[10];
    const float* b_out         = (const float*)d_in[11];
    float* out = (float*)d_out;

    unsigned short* val  = (unsigned short*)d_ws;                    // [8][LQ][32] bf16
    float*          raw  = (float*)(val + (size_t)LQ * DMODEL);      // [LQ][96] fp32
    unsigned short* outa = (unsigned short*)(raw + (size_t)LQ * 96); // [LQ][256] bf16

    dim3 blk(256);

    // 1) val = input_flatten @ W_value^T + b_value   (value layout)
    gemm_mfma<256, 4, float, false, 1><<<dim3(LQ / 64), blk, 0, stream>>>(
        input_flatten, nullptr, W_value, b_value, W_value, b_value, 256, val);

    // 2) raw = (query + query_pos) @ [W_off; W_attn]^T + [b_off; b_attn]
    gemm_mfma<96, 2, float, true, 0><<<dim3(LQ / 64), blk, 0, stream>>>(
        query, query_pos, W_off, b_off, W_attn, b_attn, 64, raw);

    // 3) softmax + bilinear sampling + point-weighted sum -> outa (bf16)
    sample_kernel<<<dim3(LQ / 8), blk, 0, stream>>>(raw, ref_points, val, outa);

    // 4) out = outa @ W_out^T + b_out
    gemm_mfma<256, 4, unsigned short, false, 0><<<dim3(LQ / 64), blk, 0, stream>>>(
        outa, nullptr, W_out, b_out, W_out, b_out, 256, out);
}

// Round 5
// 259.864 us; speedup vs baseline: 1.1497x; 1.1497x over previous
//
#include <hip/hip_runtime.h>
#include <math.h>

#define LQ 40000
#define DMODEL 256
#define NHD 8
#define NPT 4
#define DHD 32
#define HSP 200
#define WSP 200

typedef short s16x8 __attribute__((ext_vector_type(8)));
typedef float f32x4 __attribute__((ext_vector_type(4)));

__device__ __forceinline__ unsigned short f2b(float f) {
    unsigned u = __builtin_bit_cast(unsigned, f);
    u += 0x7FFFu + ((u >> 16) & 1u);   // round-to-nearest-even
    return (unsigned short)(u >> 16);
}
__device__ __forceinline__ float b2f(unsigned short u) {
    return __builtin_bit_cast(float, ((unsigned)u) << 16);
}
__device__ __forceinline__ void pk8(const float4& v0, const float4& v1,
                                    unsigned short* o) {
    o[0] = f2b(v0.x); o[1] = f2b(v0.y); o[2] = f2b(v0.z); o[3] = f2b(v0.w);
    o[4] = f2b(v1.x); o[5] = f2b(v1.y); o[6] = f2b(v1.z); o[7] = f2b(v1.w);
}

// ---------------------------------------------------------------------------
// Fragment layouts (16x16x32 bf16 MFMA):
//   A-frag buffer: elem(row, k) at  (row/16)*4096 + ks*512 + lane*8 + j
//       where ks=k/32, quad=(k/8)&3, j=k&7, lane=quad*16+(row&15).
//       A wave's frag load = one coalesced b128 per (strip, ks).
//   W-frag buffer: elem(col, k) at  slot*4096 + ks*512 + lane*8 + j
//       where slot=coltile, lane=quad*16+(col&15). Coalesced b128 per (c,ks).
// ---------------------------------------------------------------------------

// Pre-convert all weights to bf16 fragment order.
// slots: 0-15 W_value, 16-21 [W_off;W_attn] (split 64), 22-37 W_out.
__global__ __launch_bounds__(256) void convert_weights(
    const float* __restrict__ Wv, const float* __restrict__ Woff,
    const float* __restrict__ Wattn, const float* __restrict__ Wout,
    unsigned short* __restrict__ dst)
{
    int u = blockIdx.x * 256 + threadIdx.x;      // 38*8*64 = 19456 exactly
    int lane = u & 63, ks = (u >> 6) & 7, slot = u >> 9;
    int l15 = lane & 15, quad = lane >> 4;
    const float* src;
    if (slot < 16) {
        src = Wv + (size_t)(slot * 16 + l15) * 256;
    } else if (slot < 22) {
        int col = (slot - 16) * 16 + l15;
        src = (col < 64) ? Woff + (size_t)col * 256
                         : Wattn + (size_t)(col - 64) * 256;
    } else {
        src = Wout + (size_t)((slot - 22) * 16 + l15) * 256;
    }
    int k0 = ks * 32 + quad * 8;
    float4 v0 = *(const float4*)(src + k0);
    float4 v1 = *(const float4*)(src + k0 + 4);
    union { unsigned short u16[8]; uint4 v; } tmp;
    pk8(v0, v1, tmp.u16);
    *(uint4*)(dst + (size_t)u * 8) = tmp.v;
}

// Transpose fp32 row-major [+A2] -> bf16 A-fragment layout. 1 strip/block.
template <bool HasA2>
__global__ __launch_bounds__(256) void transpose_a(
    const float* __restrict__ A, const float* __restrict__ A2,
    unsigned short* __restrict__ dst)
{
    const int strip = blockIdx.x;
    const int w = threadIdx.x >> 6, lane = threadIdx.x & 63;
    const int l15 = lane & 15, quad = lane >> 4;
    const size_t rowoff = ((size_t)strip * 16 + l15) * 256;
#pragma unroll
    for (int i = 0; i < 2; ++i) {
        int ks = w * 2 + i;
        int k0 = ks * 32 + quad * 8;
        float4 v0 = *(const float4*)(A + rowoff + k0);
        float4 v1 = *(const float4*)(A + rowoff + k0 + 4);
        if constexpr (HasA2) {
            float4 w0 = *(const float4*)(A2 + rowoff + k0);
            float4 w1 = *(const float4*)(A2 + rowoff + k0 + 4);
            v0.x += w0.x; v0.y += w0.y; v0.z += w0.z; v0.w += w0.w;
            v1.x += w1.x; v1.y += w1.y; v1.z += w1.z; v1.w += w1.w;
        }
        union { unsigned short u16[8]; uint4 v; } tmp;
        pk8(v0, v1, tmp.u16);
        *(uint4*)(dst + (size_t)strip * 4096 + ks * 512 + lane * 8) = tmp.v;
    }
}

// ---------------------------------------------------------------------------
// Barrier-free row-strip GEMM. Block = 4 waves sharing one 16-row strip
// (identical A addresses -> L1 broadcast); wave owns coltiles wave*TPW..+TPW-1
// with B strip resident in registers. 2 strips per block, no LDS, no barrier.
// CMODE 0: C fp32 row-major [M x NT*16]. CMODE 1: C bf16 value layout
// [head][pixel][32ch].
// ---------------------------------------------------------------------------
template <int NT, int TPW, int CMODE>
__global__ __launch_bounds__(256, 2) void gemm_rs(
    const unsigned short* __restrict__ Af, const unsigned short* __restrict__ Wf,
    const float* __restrict__ b1, const float* __restrict__ b2, int split,
    void* __restrict__ Cv)
{
    const int t = threadIdx.x;
    const int wave = t >> 6, lane = t & 63;
    const int l15 = lane & 15, quad = lane >> 4;

    // B fragments + bias (L2-resident, coalesced b128)
    s16x8 bf[TPW][8];
    float bias[TPW];
#pragma unroll
    for (int j = 0; j < TPW; ++j) {
        bias[j] = 0.f;
        int c = wave * TPW + j;
        if (c < NT) {
#pragma unroll
            for (int ks = 0; ks < 8; ++ks)
                bf[j][ks] = *(const s16x8*)&Wf[(size_t)(c * 8 + ks) * 512 + lane * 8];
            int col = c * 16 + l15;
            bias[j] = (col < split) ? b1[col] : b2[col - split];
        }
    }

#pragma unroll
    for (int s = 0; s < 2; ++s) {
        const size_t g = (size_t)blockIdx.x * 2 + s;
        s16x8 a[8];
#pragma unroll
        for (int ks = 0; ks < 8; ++ks)
            a[ks] = *(const s16x8*)&Af[g * 4096 + ks * 512 + lane * 8];
#pragma unroll
        for (int j = 0; j < TPW; ++j) {
            int c = wave * TPW + j;
            if (c < NT) {
                f32x4 acc = (f32x4){0.f, 0.f, 0.f, 0.f};
#pragma unroll
                for (int ks = 0; ks < 8; ++ks)
                    acc = __builtin_amdgcn_mfma_f32_16x16x32_bf16(a[ks], bf[j][ks],
                                                                  acc, 0, 0, 0);
#pragma unroll
                for (int r2 = 0; r2 < 4; ++r2) {
                    size_t row = g * 16 + quad * 4 + r2;
                    float v = acc[r2] + bias[j];
                    if constexpr (CMODE == 1) {
                        ((unsigned short*)Cv)[(((size_t)(c >> 1) * LQ + row) << 5)
                                              + ((c & 1) << 4) + l15] = f2b(v);
                    } else {
                        ((float*)Cv)[row * (NT * 16) + c * 16 + l15] = v;
                    }
                }
            }
        }
    }
}

// ---------------------------------------------------------------------------
// Deformable sampling (R3 structure). Block = 256 thr, 8 queries per block.
// Phase 1: thread (qi,h,p) -> fused corner weights + clamped pixel offsets.
// Phase 2: thread (qq,h,d8): 2 queries, uint2 gathers from value
//          [head][pixel][32ch]; writes outa in A-FRAGMENT layout for GEMM4.
// ---------------------------------------------------------------------------
__global__ __launch_bounds__(256) void sample_kernel(
    const float* __restrict__ raw, const float* __restrict__ rp,
    const unsigned short* __restrict__ value, unsigned short* __restrict__ outa)
{
    __shared__ int4   sIdx[8][8][4];
    __shared__ float4 sW[8][8][4];

    const int t = threadIdx.x;
    {   // phase 1
        const int qi = t >> 5, h = (t >> 2) & 7, p = t & 3;
        const int q = blockIdx.x * 8 + qi;
        const float* r = raw + (size_t)q * 96;
        float l0 = r[64 + h * 4 + 0], l1 = r[64 + h * 4 + 1];
        float l2 = r[64 + h * 4 + 2], l3 = r[64 + h * 4 + 3];
        float mx = fmaxf(fmaxf(l0, l1), fmaxf(l2, l3));
        float e0 = __expf(l0 - mx), e1 = __expf(l1 - mx);
        float e2 = __expf(l2 - mx), e3 = __expf(l3 - mx);
        float inv = 1.f / (e0 + e1 + e2 + e3);
        float ep = (p == 0) ? e0 : (p == 1) ? e1 : (p == 2) ? e2 : e3;
        float wp = ep * inv;

        float x = rp[(size_t)q * 2 + 0] * (float)WSP - 0.5f + r[h * 8 + p * 2 + 0];
        float y = rp[(size_t)q * 2 + 1] * (float)HSP - 0.5f + r[h * 8 + p * 2 + 1];
        float x0f = floorf(x), y0f = floorf(y);
        int x0 = (int)x0f, y0 = (int)y0f;
        float lw = x - x0f, lh = y - y0f;
        float cw[4] = {(1.f - lh) * (1.f - lw), (1.f - lh) * lw,
                       lh * (1.f - lw), lh * lw};
        int4 I; float4 W;
        int* Ip = &I.x; float* Wp = &W.x;
#pragma unroll
        for (int c = 0; c < 4; ++c) {
            int cx = x0 + (c & 1), cy = y0 + (c >> 1);
            bool valid = (cx >= 0) & (cx < WSP) & (cy >= 0) & (cy < HSP);
            int ccx = cx < 0 ? 0 : (cx > WSP - 1 ? WSP - 1 : cx);
            int ccy = cy < 0 ? 0 : (cy > HSP - 1 ? HSP - 1 : cy);
            Ip[c] = (ccy * WSP + ccx) * DHD;   // element offset within head plane
            Wp[c] = valid ? cw[c] * wp : 0.f;
        }
        sIdx[qi][h][p] = I;
        sW[qi][h][p] = W;
    }
    __syncthreads();

    // phase 2
    const int qq = t >> 6, h = (t >> 3) & 7, d8 = t & 7;
    const unsigned short* vp = value + (size_t)h * LQ * DHD + d8 * 4;
#pragma unroll
    for (int e = 0; e < 2; ++e) {
        int qi = qq * 2 + e;
        float a0 = 0.f, a1 = 0.f, a2 = 0.f, a3 = 0.f;
#pragma unroll
        for (int p = 0; p < 4; ++p) {
            int4 I = sIdx[qi][h][p];
            float4 W = sW[qi][h][p];
            uint2 g0 = *(const uint2*)(vp + I.x);
            uint2 g1 = *(const uint2*)(vp + I.y);
            uint2 g2 = *(const uint2*)(vp + I.z);
            uint2 g3 = *(const uint2*)(vp + I.w);
            a0 += W.x * b2f((unsigned short)g0.x);
            a1 += W.x * b2f((unsigned short)(g0.x >> 16));
            a2 += W.x * b2f((unsigned short)g0.y);
            a3 += W.x * b2f((unsigned short)(g0.y >> 16));
            a0 += W.y * b2f((unsigned short)g1.x);
            a1 += W.y * b2f((unsigned short)(g1.x >> 16));
            a2 += W.y * b2f((unsigned short)g1.y);
            a3 += W.y * b2f((unsigned short)(g1.y >> 16));
            a0 += W.z * b2f((unsigned short)g2.x);
            a1 += W.z * b2f((unsigned short)(g2.x >> 16));
            a2 += W.z * b2f((unsigned short)g2.y);
            a3 += W.z * b2f((unsigned short)(g2.y >> 16));
            a0 += W.w * b2f((unsigned short)g3.x);
            a1 += W.w * b2f((unsigned short)(g3.x >> 16));
            a2 += W.w * b2f((unsigned short)g3.y);
            a3 += W.w * b2f((unsigned short)(g3.y >> 16));
        }
        int q = blockIdx.x * 8 + qi;
        // A-fragment layout write: c = h*32 + d8*4 + {0..3}
        size_t off = (size_t)(q >> 4) * 4096 + h * 512 + (d8 >> 1) * 128
                   + (q & 15) * 8 + (d8 & 1) * 4;
        union { unsigned short u16[4]; uint2 v; } o;
        o.u16[0] = f2b(a0); o.u16[1] = f2b(a1);
        o.u16[2] = f2b(a2); o.u16[3] = f2b(a3);
        *(uint2*)&outa[off] = o.v;
    }
}

extern "C" void kernel_launch(void* const* d_in, const int* in_sizes, int n_in,
                              void* d_out, int out_size, void* d_ws, size_t ws_size,
                              hipStream_t stream)
{
    const float* query         = (const float*)d_in[0];
    const float* query_pos     = (const float*)d_in[1];
    const float* ref_points    = (const float*)d_in[2];
    const float* input_flatten = (const float*)d_in[3];
    const float* W_value       = (const float*)d_in[4];
    const float* b_value       = (const float*)d_in[5];
    const float* W_off         = (const float*)d_in[6];
    const float* b_off         = (const float*)d_in[7];
    const float* W_attn        = (const float*)d_in[8];
    const float* b_attn        = (const float*)d_in[9];
    const float* W_out         = (const float*)d_in[10];
    const float* b_out         = (const float*)d_in[11];
    float* out = (float*)d_out;

    // workspace: val 20.48MB | raw 15.36MB | outa 20.48MB | Abuf 20.48MB | wf 0.31MB
    unsigned short* val  = (unsigned short*)d_ws;                     // [8][LQ][32]
    float*          raw  = (float*)(val + (size_t)LQ * DMODEL);       // [LQ][96]
    unsigned short* outa = (unsigned short*)(raw + (size_t)LQ * 96);  // A-frag layout
    unsigned short* Abuf = outa + (size_t)LQ * DMODEL;                // A-frag layout
    unsigned short* wf   = Abuf + (size_t)LQ * DMODEL;                // W-frag bf16
    unsigned short* wfv  = wf;              // slots 0-15
    unsigned short* wfoa = wf + 65536;      // slots 16-21
    unsigned short* wfo  = wf + 90112;      // slots 22-37

    dim3 blk(256);

    // 0) weights -> bf16 fragment order
    convert_weights<<<dim3(76), blk, 0, stream>>>(W_value, W_off, W_attn, W_out, wf);

    // 1) Abuf = frag(input_flatten);  val = Abuf @ Wv^T + b  (value layout)
    transpose_a<false><<<dim3(LQ / 16), blk, 0, stream>>>(input_flatten, nullptr, Abuf);
    gemm_rs<16, 4, 1><<<dim3(LQ / 32), blk, 0, stream>>>(
        Abuf, wfv, b_value, b_value, 256, val);

    // 2) Abuf = frag(query + query_pos);  raw = Abuf @ [Woff;Wattn]^T + [boff;battn]
    transpose_a<true><<<dim3(LQ / 16), blk, 0, stream>>>(query, query_pos, Abuf);
    gemm_rs<6, 2, 0><<<dim3(LQ / 32), blk, 0, stream>>>(
        Abuf, wfoa, b_off, b_attn, 64, raw);

    // 3) sampling -> outa (A-fragment layout)
    sample_kernel<<<dim3(LQ / 8), blk, 0, stream>>>(raw, ref_points, val, outa);

    // 4) out = outa @ W_out^T + b_out
    gemm_rs<16, 4, 0><<<dim3(LQ / 32), blk, 0, stream>>>(
        outa, wfo, b_out, b_out, 256, out);
}